// Round 9
// baseline (1831.845 us; speedup 1.0000x reference)
//
#include <hip/hip_runtime.h>
#include <hip/hip_fp16.h>
#include <hip/hip_cooperative_groups.h>
#include <math.h>

namespace cg = cooperative_groups;

#define HD 64       // hidden dim H
#define MAXNBK 512  // max dst-range buckets (128 nodes per bucket)
#define NPREB 512   // hist/bucket chunk blocks
#define MEGAGRID 1024  // 4 blocks/CU x 256 CU (guaranteed co-resident w/ launch_bounds(256,4))

typedef unsigned long long u64;
typedef _Float16 f16;
typedef _Float16 f16x8 __attribute__((ext_vector_type(8)));
typedef float f32x4 __attribute__((ext_vector_type(4)));

__device__ __forceinline__ u64 pack_rec(int src, float a0, float a1, float a2) {
    return (u64)(src & 0xFFFF)
         | ((u64)__half_as_ushort(__float2half(a0)) << 16)
         | ((u64)__half_as_ushort(__float2half(a1)) << 32)
         | ((u64)__half_as_ushort(__float2half(a2)) << 48);
}

// ---------------- init: zero bcnt/gacc/tick ; su = We@ae ; WT_l = f16(W_l^T) ----------------
__global__ void k_init(int* bcnt, float* gacc, int* tick, float* suG,
                       const float* We1, const float* ae1,
                       const float* We2, const float* ae2,
                       const float* We3, const float* ae3, int FE,
                       const float* W1, const float* W2, const float* W3,
                       f16* WT0, f16* WT1, f16* WT2, int FIN) {
    int t = threadIdx.x;
    for (int i = t; i < MAXNBK; i += 256) bcnt[i] = 0;
    if (t < HD) gacc[t] = 0.f;
    if (t == 0) *tick = 0;
    if (t < 3 * FE) {
        int l = t / FE, f = t % FE;
        const float* We = (l == 0) ? We1 : (l == 1) ? We2 : We3;
        const float* ae = (l == 0) ? ae1 : (l == 1) ? ae2 : ae3;
        float s = 0.f;
        for (int hh = 0; hh < HD; ++hh) s += We[f * HD + hh] * ae[hh];
        suG[t] = s;
    }
    // transpose W (row-major [K][64]) -> WT (f16 [64][K]); coalesced reads
    for (int i = t; i < HD * FIN; i += 256) {
        int k = i >> 6, c = i & 63;
        WT0[c * FIN + k] = (f16)W1[i];
    }
    for (int i = t; i < HD * HD; i += 256) {
        int k = i >> 6, c = i & 63;
        WT1[c * HD + k] = (f16)W2[i];
        WT2[c * HD + k] = (f16)W3[i];
    }
}

// ---------------- fused: [0,nt) alpha tiles (1024 edges, LDS-free stream) ;
//                  [nt,+NPREB) dst-bucket histogram (writes bhist slice + bcnt) --------------
__global__ void k_pre(const int* __restrict__ ei, const float* __restrict__ ea,
                      const float* __restrict__ suG,
                      int E, int FE, u64* __restrict__ recE,
                      float* __restrict__ partials,
                      int nt, int chunk, int* bcnt, int* __restrict__ bhist, int NBK) {
    extern __shared__ float lds[];
    int t = threadIdx.x;

    if (blockIdx.x >= nt) {
        int* lc = (int*)lds;
        for (int i = t; i < NBK; i += 256) lc[i] = 0;
        __syncthreads();
        int cb = blockIdx.x - nt;
        int lo = cb * chunk, hi = min(E, lo + chunk);
        for (int e = lo + t; e < hi; e += 256)
            atomicAdd(&lc[ei[E + e] >> 7], 1);
        __syncthreads();
        for (int i = t; i < NBK; i += 256) {
            int c = lc[i];
            bhist[(size_t)i * NPREB + cb] = c;
            if (c) atomicAdd(&bcnt[i], c);
        }
        return;
    }

    size_t ebase = (size_t)blockIdx.x * 1024;
    float4 c0 = make_float4(0.f, 0.f, 0.f, 0.f), c1 = c0, c2 = c0, c3 = c0;

#pragma unroll
    for (int k = 0; k < 4; ++k) {
        size_t e = ebase + (size_t)k * 256 + t;
        bool ok = e < (size_t)E;
        size_t ec = ok ? e : (size_t)(E - 1);
        const float4* row = (const float4*)(ea + ec * FE);
        float4 r0 = row[0], r1 = row[1], r2 = row[2], r3 = row[3];
        int src = ei[ec];
        float rr[16];
        *(float4*)&rr[0] = r0; *(float4*)&rr[4] = r1;
        *(float4*)&rr[8] = r2; *(float4*)&rr[12] = r3;
        float a0 = 0.f, a1 = 0.f, a2 = 0.f;
#pragma unroll
        for (int f = 0; f < 16; ++f) {
            float v = rr[f];
            a0 += v * suG[f];
            a1 += v * suG[16 + f];
            a2 += v * suG[32 + f];
        }
        if (ok) {
            c0.x += r0.x; c0.y += r0.y; c0.z += r0.z; c0.w += r0.w;
            c1.x += r1.x; c1.y += r1.y; c1.z += r1.z; c1.w += r1.w;
            c2.x += r2.x; c2.y += r2.y; c2.z += r2.z; c2.w += r2.w;
            c3.x += r3.x; c3.y += r3.y; c3.z += r3.z; c3.w += r3.w;
            recE[e] = pack_rec(src, a0, a1, a2);
        }
    }

    float* cs = lds;                 // 256*17
    float* cw = lds + 256 * 17;      // 64
    cs[t * 17 + 0] = c0.x; cs[t * 17 + 1] = c0.y; cs[t * 17 + 2] = c0.z; cs[t * 17 + 3] = c0.w;
    cs[t * 17 + 4] = c1.x; cs[t * 17 + 5] = c1.y; cs[t * 17 + 6] = c1.z; cs[t * 17 + 7] = c1.w;
    cs[t * 17 + 8] = c2.x; cs[t * 17 + 9] = c2.y; cs[t * 17 + 10] = c2.z; cs[t * 17 + 11] = c2.w;
    cs[t * 17 + 12] = c3.x; cs[t * 17 + 13] = c3.y; cs[t * 17 + 14] = c3.z; cs[t * 17 + 15] = c3.w;
    __syncthreads();
    if (t < 64) {
        int f = t & 15, g = t >> 4;
        float s = 0.f;
        for (int r = 0; r < 64; ++r) s += cs[(g * 64 + r) * 17 + f];
        cw[t] = s;
    }
    __syncthreads();
    if (t < 16)
        partials[blockIdx.x * 16 + t] = cw[t] + cw[16 + t] + cw[32 + t] + cw[48 + t];
}

// ---------------- partials -> sE ; bucket bases from bcnt scan (2 bins/thread) ----------------
__global__ void k_u2(const float* __restrict__ partials, int NB,
                     const float* __restrict__ suG,
                     float* sE, int FE, float invE,
                     const int* __restrict__ bcnt,
                     int* bfill /* padded */, int* bbase, int NBK, int E) {
    __shared__ float red[256 * 4];
    __shared__ float mea[16];
    __shared__ int ib[256];
    int t = threadIdx.x;
    const float4* p4 = (const float4*)partials;
    int tot4 = NB * 4;
    float4 acc = make_float4(0.f, 0.f, 0.f, 0.f);
    for (int i = t; i < tot4; i += 256) {
        float4 v = p4[i];
        acc.x += v.x; acc.y += v.y; acc.z += v.z; acc.w += v.w;
    }
    red[t * 4 + 0] = acc.x; red[t * 4 + 1] = acc.y;
    red[t * 4 + 2] = acc.z; red[t * 4 + 3] = acc.w;
    int i0 = 2 * t, i1 = 2 * t + 1;
    int c0 = (i0 < NBK) ? bcnt[i0] : 0;
    int c1 = (i1 < NBK) ? bcnt[i1] : 0;
    ib[t] = c0 + c1;
    __syncthreads();
    for (int d = 1; d < 256; d <<= 1) {
        int x = (t >= d) ? ib[t - d] : 0;
        __syncthreads();
        ib[t] += x;
        __syncthreads();
    }
    int excl = ib[t] - (c0 + c1);
    if (i0 < NBK) { bbase[i0] = excl;      bfill[i0 * 16] = excl; }
    if (i1 < NBK) { bbase[i1] = excl + c0; bfill[i1 * 16] = excl + c0; }
    if (t == 0) bbase[NBK] = E;
    if (t < 16) {
        int q = t >> 2, j = t & 3;
        float s = 0.f;
        for (int k = 0; k < 64; ++k) s += red[(q + k * 4) * 4 + j];
        mea[q * 4 + j] = s * invE;  // mean_ea
    }
    __syncthreads();
    if (t < 3) {
        float a = 0.f;
        for (int f = 0; f < FE; ++f) a += mea[f] * suG[t * FE + f];
        sE[t] = a;
    }
}

// ---------------- pass 2: bin records by dst bucket (counts from bhist) ----------------------
__global__ void k_bucket(const int* __restrict__ ei, const u64* __restrict__ recE,
                         int E, int chunk, int* bfill /* padded */,
                         u64* __restrict__ binned, unsigned char* __restrict__ bdstl,
                         int NBK, const int* __restrict__ bhist) {
    __shared__ int gb[MAXNBK], lrank[MAXNBK];
    int t = threadIdx.x;
    int cb = blockIdx.x;
    for (int i = t; i < NBK; i += 256) {
        int c = bhist[(size_t)i * NPREB + cb];
        lrank[i] = 0;
        gb[i] = c ? atomicAdd(&bfill[i * 16], c) : 0;
    }
    __syncthreads();
    int lo = cb * chunk, hi = min(E, lo + chunk);
    for (int e = lo + t; e < hi; e += 256) {
        u64 r = recE[e];
        int dst = ei[E + e];
        int b = dst >> 7;
        int rank = atomicAdd(&lrank[b], 1);
        int pos = gb[b] + rank;
        binned[pos] = r;
        bdstl[pos] = (unsigned char)(dst & 127);
    }
}

// ---------------- pass 3: per-128-node-bucket hist+scan -> row_ptr, self-loop, distribute ----
__global__ void k_sort(const int* __restrict__ bbase, const u64* __restrict__ binned,
                       const unsigned char* __restrict__ bdstl,
                       const float* __restrict__ sE,
                       int* __restrict__ row_ptr,
                       u64* __restrict__ rec, int N, int E) {
    __shared__ int lcnt[128], lfill[128];
    int b = blockIdx.x, t = threadIdx.x;
    int base = bbase[b], nrec = bbase[b + 1] - base;
    if (t < 128) lcnt[t] = 0;
    __syncthreads();
    for (int i = t; i < nrec; i += 256)
        atomicAdd(&lcnt[bdstl[base + i]], 1);
    __syncthreads();
    int v = (t < 128) ? lcnt[t] : 0;
    for (int d = 1; d < 128; d <<= 1) {
        int x = (t >= d && t < 128) ? lcnt[t - d] : 0;
        __syncthreads();
        if (t < 128) lcnt[t] += x;
        __syncthreads();
    }
    int gnode = (b << 7) + t;
    if (t < 128) {
        int rp = base + gnode + (lcnt[t] - v);
        if (gnode < N) {
            row_ptr[gnode] = rp;
            rec[rp] = pack_rec(gnode, sE[0], sE[1], sE[2]);  // self-loop at slot 0
        }
        lfill[t] = rp + 1;
    }
    if (b == 0 && t == 0) row_ptr[N] = E + N;
    __syncthreads();
    for (int i = t; i < nrec; i += 256) {
        u64 r = binned[base + i];
        int dl = bdstl[base + i];
        int p = atomicAdd(&lfill[dl], 1);
        rec[p] = r;
    }
}

// ================= shared device bodies: gemm tile / aggr group =================
__device__ __forceinline__ void gemm_tile_dev(char* smem, int nb,
        const void* __restrict__ xin, int in_f16, const f16* __restrict__ WT,
        const float* __restrict__ a_s, const float* __restrict__ a_d,
        __half* __restrict__ h, float* __restrict__ as_n, float* __restrict__ ad_n,
        int N, int K) {
    const int SK = K + 8;
    f16* xs = (f16*)smem;          // 64*SK
    f16* wt = xs + 64 * SK;        // 64*SK
    int t = threadIdx.x;
    int nK4 = K >> 2;
    __syncthreads();               // protect LDS reuse across grid-stride iterations
    if (in_f16) {
        const __half* xh = (const __half*)xin;
        for (int i = t; i < 64 * nK4; i += 256) {
            int row = i / nK4, c4 = i % nK4;
            int gr = nb + row; if (gr >= N) gr = N - 1;
            u64 v = ((const u64*)(xh + (size_t)gr * K))[c4];
            *(u64*)&xs[row * SK + c4 * 4] = v;
        }
    } else {
        const float* xf = (const float*)xin;
        for (int i = t; i < 64 * nK4; i += 256) {
            int row = i / nK4, c4 = i % nK4;
            int gr = nb + row; if (gr >= N) gr = N - 1;
            float4 v = ((const float4*)(xf + (size_t)gr * K))[c4];
            f16* p = &xs[row * SK + c4 * 4];
            p[0] = (f16)v.x; p[1] = (f16)v.y; p[2] = (f16)v.z; p[3] = (f16)v.w;
        }
    }
    // wt copy from pre-transposed f16 WT (no cvt)
    for (int i = t; i < 64 * nK4; i += 256) {
        int c = i / nK4, c4 = i % nK4;
        u64 v = ((const u64*)(WT + (size_t)c * K))[c4];
        *(u64*)&wt[c * SK + c4 * 4] = v;
    }
    __syncthreads();

    int wv = t >> 6, lane = t & 63;
    int m = lane & 15, quad = lane >> 4;
    int rowA = wv * 16 + m;

    f32x4 acc[4];
#pragma unroll
    for (int ct = 0; ct < 4; ++ct) acc[ct] = (f32x4){0.f, 0.f, 0.f, 0.f};

    for (int ks = 0; ks < (K >> 5); ++ks) {
        f16x8 a = *(const f16x8*)&xs[rowA * SK + ks * 32 + quad * 8];
#pragma unroll
        for (int ct = 0; ct < 4; ++ct) {
            f16x8 bf = *(const f16x8*)&wt[(ct * 16 + m) * SK + ks * 32 + quad * 8];
            acc[ct] = __builtin_amdgcn_mfma_f32_16x16x32_f16(a, bf, acc[ct], 0, 0, 0);
        }
    }

    {
        float as_c[4], ad_c[4];
#pragma unroll
        for (int ct = 0; ct < 4; ++ct) {
            as_c[ct] = a_s[ct * 16 + m];
            ad_c[ct] = a_d[ct * 16 + m];
        }
#pragma unroll
        for (int r = 0; r < 4; ++r) {
            float ps = acc[0][r] * as_c[0] + acc[1][r] * as_c[1]
                     + acc[2][r] * as_c[2] + acc[3][r] * as_c[3];
            float pd = acc[0][r] * ad_c[0] + acc[1][r] * ad_c[1]
                     + acc[2][r] * ad_c[2] + acc[3][r] * ad_c[3];
#pragma unroll
            for (int dd = 8; dd; dd >>= 1) {
                ps += __shfl_xor(ps, dd, 64);
                pd += __shfl_xor(pd, dd, 64);
            }
            if (m == 0) {
                int gr = nb + wv * 16 + quad * 4 + r;
                if (gr < N) { as_n[gr] = ps; ad_n[gr] = pd; }
            }
        }
    }

    __syncthreads();
    f16* ht = xs;
    const int HS = 72;
#pragma unroll
    for (int ct = 0; ct < 4; ++ct)
#pragma unroll
        for (int r = 0; r < 4; ++r) {
            int rl = wv * 16 + quad * 4 + r;
            ht[rl * HS + ct * 16 + m] = (f16)acc[ct][r];
        }
    __syncthreads();
    {
        int row = t >> 2, cb = (t & 3) * 16;
        int gr = nb + row;
        if (gr < N) {
            ulonglong2 v0 = *(const ulonglong2*)&ht[row * HS + cb];
            ulonglong2 v1 = *(const ulonglong2*)&ht[row * HS + cb + 8];
            *(ulonglong2*)(h + (size_t)gr * HD + cb) = v0;
            *(ulonglong2*)(h + (size_t)gr * HD + cb + 8) = v1;
        }
    }
}

__device__ __forceinline__ void aggr_group_dev(int g, int l,
        const __half* __restrict__ h, const float* __restrict__ as_n,
        const float* __restrict__ ad_n, const int* __restrict__ row_ptr,
        const u64* __restrict__ rec, const float* __restrict__ b,
        __half* __restrict__ x_out, float* __restrict__ emb, int N, int first) {
    int wave = threadIdx.x >> 6, lane = threadIdx.x & 63;
    int hl = lane & 31;
    int n = g * 8 + wave * 2 + (lane >> 5);
    int nc = min(n, N - 1);
    int base = row_ptr[nc], end = row_ptr[nc + 1];
    float adv = ad_n[nc];
    const int shift = 16 * (l + 1);
    int qq = (lane >> 3) & 3, fo = lane & 7;
    int nch = (end - base + 31) >> 5;
    int nchmax = max(nch, __shfl_xor(nch, 32, 64));
    float m = -INFINITY, d = 0.f;
    float acc[8];
#pragma unroll
    for (int k = 0; k < 8; ++k) acc[k] = 0.f;

    for (int ch = 0; ch < nchmax; ++ch) {
        int c = base + (ch << 5);
        int cnt = min(32, end - c);
        float a = -INFINITY;
        int s = 0;
        if (hl < cnt) {
            u64 r = rec[c + hl];
            s = (int)(r & 0xFFFFull);
            float aE = __half2float(__ushort_as_half((unsigned short)(r >> shift)));
            a = as_n[s] + adv + aE;
            a = (a > 0.f) ? a : 0.2f * a;
        }
        float mc = a;
#pragma unroll
        for (int dd = 16; dd; dd >>= 1) mc = fmaxf(mc, __shfl_xor(mc, dd, 64));
        float mn = fmaxf(m, mc);
        float w = (hl < cnt) ? __expf(a - mn) : 0.f;
        float dc = w;
#pragma unroll
        for (int dd = 16; dd; dd >>= 1) dc += __shfl_xor(dc, dd, 64);
        float sc = __expf(m - mn);
        d = d * sc + dc;
#pragma unroll
        for (int k = 0; k < 8; ++k) acc[k] *= sc;
        m = mn;
        int iters = (max(cnt, 0) + 3) >> 2;
        for (int j4 = 0; j4 < iters; ++j4) {
            int j = (j4 << 2) + qq;
            int sl = (lane & 32) + j;
            int sj = __shfl(s, sl, 64);
            float wj = __shfl(w, sl, 64);
            uint4 hv = *(const uint4*)(h + (size_t)sj * HD + (fo << 3));
            asm("v_fma_mix_f32 %0, %1, %2, %0 op_sel:[0,0,0] op_sel_hi:[0,1,0]"
                : "+v"(acc[0]) : "v"(wj), "v"(hv.x));
            asm("v_fma_mix_f32 %0, %1, %2, %0 op_sel:[0,1,0] op_sel_hi:[0,1,0]"
                : "+v"(acc[1]) : "v"(wj), "v"(hv.x));
            asm("v_fma_mix_f32 %0, %1, %2, %0 op_sel:[0,0,0] op_sel_hi:[0,1,0]"
                : "+v"(acc[2]) : "v"(wj), "v"(hv.y));
            asm("v_fma_mix_f32 %0, %1, %2, %0 op_sel:[0,1,0] op_sel_hi:[0,1,0]"
                : "+v"(acc[3]) : "v"(wj), "v"(hv.y));
            asm("v_fma_mix_f32 %0, %1, %2, %0 op_sel:[0,0,0] op_sel_hi:[0,1,0]"
                : "+v"(acc[4]) : "v"(wj), "v"(hv.z));
            asm("v_fma_mix_f32 %0, %1, %2, %0 op_sel:[0,1,0] op_sel_hi:[0,1,0]"
                : "+v"(acc[5]) : "v"(wj), "v"(hv.z));
            asm("v_fma_mix_f32 %0, %1, %2, %0 op_sel:[0,0,0] op_sel_hi:[0,1,0]"
                : "+v"(acc[6]) : "v"(wj), "v"(hv.w));
            asm("v_fma_mix_f32 %0, %1, %2, %0 op_sel:[0,1,0] op_sel_hi:[0,1,0]"
                : "+v"(acc[7]) : "v"(wj), "v"(hv.w));
        }
    }

#pragma unroll
    for (int k = 0; k < 8; ++k) {
        acc[k] += __shfl_xor(acc[k], 8, 64);
        acc[k] += __shfl_xor(acc[k], 16, 64);
    }
    if (hl < 8 && n < N) {
        float inv = 1.f / (d + 1e-16f);
        const float4* b4p = (const float4*)(b + (fo << 3));
        float4 b0 = b4p[0], b1 = b4p[1];
        float bb[8] = {b0.x, b0.y, b0.z, b0.w, b1.x, b1.y, b1.z, b1.w};
        float vv[8];
#pragma unroll
        for (int k = 0; k < 8; ++k) {
            float v = acc[k] * inv + bb[k];
            vv[k] = (v > 0.f) ? v : expm1f(v);
        }
        union { unsigned short us[8]; ulonglong2 u2; } ou;
#pragma unroll
        for (int k = 0; k < 8; ++k) ou.us[k] = __half_as_ushort(__float2half(vv[k]));
        *(ulonglong2*)(x_out + (size_t)n * HD + (fo << 3)) = ou.u2;
        float4* ep = (float4*)(emb + (size_t)n * HD + (fo << 3));
        if (first) {
            ep[0] = make_float4(vv[0], vv[1], vv[2], vv[3]);
            ep[1] = make_float4(vv[4], vv[5], vv[6], vv[7]);
        } else {
            float4 e0 = ep[0], e1 = ep[1];
            e0.x += vv[0]; e0.y += vv[1]; e0.z += vv[2]; e0.w += vv[3];
            e1.x += vv[4]; e1.y += vv[5]; e1.z += vv[6]; e1.w += vv[7];
            ep[0] = e0; ep[1] = e1;
        }
    }
}

// ================= cooperative mega-kernel: {gemm, aggr}x3 + red =================
struct MA {
    const float* x; __half* x_cur; __half* h;
    float* as_n; float* ad_n;
    const int* rowp; const u64* rec;
    const f16* WT[3];
    const float* a_s[3]; const float* a_d[3]; const float* bb[3];
    float* emb; float* gacc;
    int N, K0, Gg, ngroups;
};

__global__ __launch_bounds__(256, 4) void k_mega(MA a) {
    extern __shared__ char smem[];
    cg::grid_group grid = cg::this_grid();
    for (int l = 0; l < 3; ++l) {
        const void* xin = (l == 0) ? (const void*)a.x : (const void*)a.x_cur;
        int in_f16 = (l > 0);
        int K = (l == 0) ? a.K0 : HD;
        for (int tb = blockIdx.x; tb < a.Gg; tb += gridDim.x)
            gemm_tile_dev(smem, tb * 64, xin, in_f16, a.WT[l], a.a_s[l], a.a_d[l],
                          a.h, a.as_n, a.ad_n, a.N, K);
        __threadfence();
        grid.sync();
        for (int g = blockIdx.x; g < a.ngroups; g += gridDim.x)
            aggr_group_dev(g, l, a.h, a.as_n, a.ad_n, a.rowp, a.rec, a.bb[l],
                           a.x_cur, a.emb, a.N, (l == 0) ? 1 : 0);
        __threadfence();
        grid.sync();
    }
    // red: column sums of emb -> gacc, then block 0 writes graph embedding
    {
        float* rl = (float*)smem;
        int f = threadIdx.x & 63, w = threadIdx.x >> 6;
        float s = 0.f;
        for (int n = blockIdx.x * 4 + w; n < a.N; n += gridDim.x * 4)
            s += a.emb[(size_t)n * HD + f];
        __syncthreads();           // smem reuse
        rl[threadIdx.x] = s;
        __syncthreads();
        if (w == 0) {
            float v = rl[f] + rl[64 + f] + rl[128 + f] + rl[192 + f];
            atomicAdd(&a.gacc[f], v);
        }
    }
    __threadfence();
    grid.sync();
    if (blockIdx.x == 0 && threadIdx.x < HD)
        a.emb[(size_t)a.N * HD + threadIdx.x] = a.gacc[threadIdx.x] / (float)a.N;
}

// ================= fallback (non-cooperative) kernels =================
__global__ void k_gemm(const void* __restrict__ xin, int in_f16,
                       const f16* __restrict__ WT,
                       const float* __restrict__ a_s, const float* __restrict__ a_d,
                       __half* __restrict__ h, float* __restrict__ as_n,
                       float* __restrict__ ad_n, int N, int K) {
    extern __shared__ char smem[];
    gemm_tile_dev(smem, blockIdx.x * 64, xin, in_f16, WT, a_s, a_d, h, as_n, ad_n, N, K);
}

__global__ void k_aggr(const __half* __restrict__ h, const float* __restrict__ as_n,
                       const float* __restrict__ ad_n, const int* __restrict__ row_ptr,
                       const u64* __restrict__ rec, int l,
                       const float* __restrict__ b, __half* __restrict__ x_out,
                       float* __restrict__ emb, int N, int first) {
    aggr_group_dev(blockIdx.x, l, h, as_n, ad_n, row_ptr, rec, b, x_out, emb, N, first);
}

__global__ void k_red(float* __restrict__ emb, float* __restrict__ gacc,
                      int* __restrict__ tick, int N) {
    __shared__ float lds[256];
    __shared__ int lastf;
    int f = threadIdx.x & 63, w = threadIdx.x >> 6;
    float s = 0.f;
    for (int n = blockIdx.x * 4 + w; n < N; n += gridDim.x * 4)
        s += emb[(size_t)n * HD + f];
    lds[threadIdx.x] = s;
    __syncthreads();
    if (w == 0) {
        float v = lds[f] + lds[64 + f] + lds[128 + f] + lds[192 + f];
        atomicAdd(&gacc[f], v);
    }
    __syncthreads();
    __threadfence();
    if (threadIdx.x == 0)
        lastf = (atomicAdd(tick, 1) == (int)gridDim.x - 1);
    __syncthreads();
    if (lastf && threadIdx.x < HD) {
        float g = __hip_atomic_load(&gacc[threadIdx.x], __ATOMIC_RELAXED,
                                    __HIP_MEMORY_SCOPE_AGENT);
        emb[(size_t)N * HD + threadIdx.x] = g / (float)N;
    }
}

extern "C" void kernel_launch(void* const* d_in, const int* in_sizes, int n_in,
                              void* d_out, int out_size, void* d_ws, size_t ws_size,
                              hipStream_t stream) {
    const float* x = (const float*)d_in[0];
    const int* ei = (const int*)d_in[1];
    const float* ea = (const float*)d_in[2];

    const int FIN = in_sizes[3] / HD;       // W1 is [F_IN, 64]
    const int N = in_sizes[0] / FIN;
    const int E = in_sizes[1] / 2;
    const int FE = in_sizes[2] / E;
    const int NBK = (N + 127) >> 7;         // dst buckets of 128 nodes

    const float* W[3];  const float* as_[3]; const float* ad_[3];
    const float* We[3]; const float* ae_[3]; const float* bb[3];
    for (int l = 0; l < 3; ++l) {
        W[l]  = (const float*)d_in[3 + 6 * l + 0];
        as_[l] = (const float*)d_in[3 + 6 * l + 1];
        ad_[l] = (const float*)d_in[3 + 6 * l + 2];
        We[l] = (const float*)d_in[3 + 6 * l + 3];
        ae_[l] = (const float*)d_in[3 + 6 * l + 4];
        bb[l] = (const float*)d_in[3 + 6 * l + 5];
    }

    int ntiles = (E + 1023) / 1024;         // 1024-edge alpha tiles
    int chunk = (E + NPREB - 1) / NPREB;
    int Gg = (N + 63) / 64;

    // ---- workspace layout (bytes, 256-aligned) ----
    char* ws = (char*)d_ws;
    size_t off = 0;
    auto alloc = [&](size_t bytes) {
        void* p = ws + off;
        off += (bytes + 255) & ~(size_t)255;
        return p;
    };
    __half* h      = (__half*)alloc((size_t)N * HD * 2);
    __half* x_cur  = (__half*)alloc((size_t)N * HD * 2);
    float*  as_n   = (float*)alloc((size_t)N * 4);
    float*  ad_n   = (float*)alloc((size_t)N * 4);
    int*    rowp   = (int*)alloc((size_t)(N + 1) * 4);
    int*    bcnt   = (int*)alloc((size_t)MAXNBK * 4);
    int*    bfill  = (int*)alloc((size_t)MAXNBK * 16 * 4);  // padded (64B/bucket)
    int*    bbase  = (int*)alloc((size_t)(MAXNBK + 1) * 4);
    int*    bhist  = (int*)alloc((size_t)MAXNBK * NPREB * 4);  // per-chunk bin counts
    u64*    rec    = (u64*)alloc((size_t)(E + N) * 8);
    u64*    recE   = (u64*)alloc((size_t)E * 8);
    u64*    binned = (u64*)alloc((size_t)E * 8);
    unsigned char* bdstl = (unsigned char*)alloc((size_t)E);
    float*  partials = (float*)alloc((size_t)ntiles * 16 * 4);
    float*  sE     = (float*)alloc(3 * 4);
    float*  gacc   = (float*)alloc(HD * 4);
    float*  suG    = (float*)alloc(3 * 16 * 4);
    f16*    WT0    = (f16*)alloc((size_t)HD * FIN * 2);
    f16*    WT1    = (f16*)alloc((size_t)HD * HD * 2);
    f16*    WT2    = (f16*)alloc((size_t)HD * HD * 2);
    int*    tick   = (int*)alloc(4);
    (void)ws_size; (void)n_in; (void)out_size;

    float* emb = (float*)d_out;

    k_init<<<1, 256, 0, stream>>>(bcnt, gacc, tick, suG,
                                  We[0], ae_[0], We[1], ae_[1], We[2], ae_[2], FE,
                                  W[0], W[1], W[2], WT0, WT1, WT2, FIN);
    size_t pre_lds = (size_t)(256 * 17 + 64) * 4;
    k_pre<<<ntiles + NPREB, 256, pre_lds, stream>>>(ei, ea, suG, E, FE, recE, partials,
                                                    ntiles, chunk, bcnt, bhist, NBK);
    k_u2<<<1, 256, 0, stream>>>(partials, ntiles, suG, sE, FE, 1.0f / (float)E,
                                bcnt, bfill, bbase, NBK, E);
    k_bucket<<<NPREB, 256, 0, stream>>>(ei, recE, E, chunk, bfill, binned, bdstl,
                                        NBK, bhist);
    k_sort<<<NBK, 256, 0, stream>>>(bbase, binned, bdstl, sE, rowp, rec, N, E);

    // ---- cooperative mega-kernel for {gemm, aggr}x3 + red ----
    MA ma;
    ma.x = x; ma.x_cur = x_cur; ma.h = h;
    ma.as_n = as_n; ma.ad_n = ad_n;
    ma.rowp = rowp; ma.rec = rec;
    ma.WT[0] = WT0; ma.WT[1] = WT1; ma.WT[2] = WT2;
    for (int l = 0; l < 3; ++l) { ma.a_s[l] = as_[l]; ma.a_d[l] = ad_[l]; ma.bb[l] = bb[l]; }
    ma.emb = emb; ma.gacc = gacc;
    ma.N = N; ma.K0 = FIN; ma.Gg = Gg; ma.ngroups = (N + 7) / 8;

    size_t mega_lds = (size_t)(2 * 64 * (FIN + 8)) * 2;  // xs + wt at K=FIN (max phase)
    if (mega_lds < (size_t)(2 * 64 * (HD + 8)) * 2) mega_lds = (size_t)(2 * 64 * (HD + 8)) * 2;
    if (mega_lds < 256 * 4) mega_lds = 256 * 4;
    void* margs[] = {&ma};
    hipError_t merr = hipLaunchCooperativeKernel((void*)k_mega, dim3(MEGAGRID), dim3(256),
                                                 margs, (unsigned int)mega_lds, stream);
    if (merr != hipSuccess) {
        // fallback: classic dispatch chain
        for (int l = 0; l < 3; ++l) {
            const void* xin = (l == 0) ? (const void*)x : (const void*)x_cur;
            int K = (l == 0) ? FIN : HD;
            size_t ldsz = (size_t)(2 * 64 * (K + 8)) * 2;
            k_gemm<<<Gg, 256, ldsz, stream>>>(xin, (l > 0), ma.WT[l], as_[l], ad_[l],
                                              h, as_n, ad_n, N, K);
            k_aggr<<<(N + 7) / 8, 256, 0, stream>>>(h, as_n, ad_n, rowp, rec, l,
                                                    bb[l], x_cur, emb, N, (l == 0) ? 1 : 0);
        }
        k_red<<<256, 256, 0, stream>>>(emb, gacc, tick, N);
    }
}

// Round 10
// 361.915 us; speedup vs baseline: 5.0615x; 5.0615x over previous
//
#include <hip/hip_runtime.h>
#include <hip/hip_fp16.h>
#include <math.h>

#define HD 64       // hidden dim H
#define MAXNBK 512  // max dst-range buckets (128 nodes per bucket)
#define NPREB 512   // hist/bucket chunk blocks

typedef unsigned long long u64;
typedef _Float16 f16;
typedef _Float16 f16x8 __attribute__((ext_vector_type(8)));
typedef float f32x4 __attribute__((ext_vector_type(4)));

__device__ __forceinline__ u64 pack_rec(int src, float a0, float a1, float a2) {
    return (u64)(src & 0xFFFF)
         | ((u64)__half_as_ushort(__float2half(a0)) << 16)
         | ((u64)__half_as_ushort(__float2half(a1)) << 32)
         | ((u64)__half_as_ushort(__float2half(a2)) << 48);
}

// ---------------- init: zero bcnt/gacc/tick ; su = We@ae ; WT_l = f16(W_l^T) ----------------
__global__ void k_init(int* bcnt, float* gacc, int* tick, float* suG,
                       const float* We1, const float* ae1,
                       const float* We2, const float* ae2,
                       const float* We3, const float* ae3, int FE,
                       const float* W1, const float* W2, const float* W3,
                       f16* WT0, f16* WT1, f16* WT2, int FIN) {
    int t = threadIdx.x;
    for (int i = t; i < MAXNBK; i += 256) bcnt[i] = 0;
    if (t < HD) gacc[t] = 0.f;
    if (t == 0) *tick = 0;
    if (t < 3 * FE) {
        int l = t / FE, f = t % FE;
        const float* We = (l == 0) ? We1 : (l == 1) ? We2 : We3;
        const float* ae = (l == 0) ? ae1 : (l == 1) ? ae2 : ae3;
        float s = 0.f;
        for (int hh = 0; hh < HD; ++hh) s += We[f * HD + hh] * ae[hh];
        suG[t] = s;
    }
    // transpose W (row-major [K][64]) -> WT (f16 [64][K]); coalesced reads
    for (int i = t; i < HD * FIN; i += 256) {
        int k = i >> 6, c = i & 63;
        WT0[c * FIN + k] = (f16)W1[i];
    }
    for (int i = t; i < HD * HD; i += 256) {
        int k = i >> 6, c = i & 63;
        WT1[c * HD + k] = (f16)W2[i];
        WT2[c * HD + k] = (f16)W3[i];
    }
}

// ---------------- fused: [0,nt) alpha tiles (1024 edges, LDS-free stream) ;
//                  [nt,+NPREB) dst-bucket histogram (writes bhist slice + bcnt) --------------
__global__ void k_pre(const int* __restrict__ ei, const float* __restrict__ ea,
                      const float* __restrict__ suG,
                      int E, int FE, u64* __restrict__ recE,
                      float* __restrict__ partials,
                      int nt, int chunk, int* bcnt, int* __restrict__ bhist, int NBK) {
    extern __shared__ float lds[];
    int t = threadIdx.x;

    if (blockIdx.x >= nt) {
        // ---- dst-bucket histogram chunk ----
        int* lc = (int*)lds;
        for (int i = t; i < NBK; i += 256) lc[i] = 0;
        __syncthreads();
        int cb = blockIdx.x - nt;
        int lo = cb * chunk, hi = min(E, lo + chunk);
        for (int e = lo + t; e < hi; e += 256)
            atomicAdd(&lc[ei[E + e] >> 7], 1);
        __syncthreads();
        for (int i = t; i < NBK; i += 256) {
            int c = lc[i];
            bhist[(size_t)i * NPREB + cb] = c;   // bin-major slice for k_bucket
            if (c) atomicAdd(&bcnt[i], c);       // totals for k_u2
        }
        return;
    }

    // ---- alpha tile: 1024 edges, 4 per thread, registers only ----
    size_t ebase = (size_t)blockIdx.x * 1024;
    float4 c0 = make_float4(0.f, 0.f, 0.f, 0.f), c1 = c0, c2 = c0, c3 = c0;

#pragma unroll
    for (int k = 0; k < 4; ++k) {
        size_t e = ebase + (size_t)k * 256 + t;
        bool ok = e < (size_t)E;
        size_t ec = ok ? e : (size_t)(E - 1);
        const float4* row = (const float4*)(ea + ec * FE);
        float4 r0 = row[0], r1 = row[1], r2 = row[2], r3 = row[3];
        int src = ei[ec];
        float rr[16];
        *(float4*)&rr[0] = r0; *(float4*)&rr[4] = r1;
        *(float4*)&rr[8] = r2; *(float4*)&rr[12] = r3;
        float a0 = 0.f, a1 = 0.f, a2 = 0.f;
#pragma unroll
        for (int f = 0; f < 16; ++f) {
            float v = rr[f];
            a0 += v * suG[f];
            a1 += v * suG[16 + f];
            a2 += v * suG[32 + f];
        }
        if (ok) {
            c0.x += r0.x; c0.y += r0.y; c0.z += r0.z; c0.w += r0.w;
            c1.x += r1.x; c1.y += r1.y; c1.z += r1.z; c1.w += r1.w;
            c2.x += r2.x; c2.y += r2.y; c2.z += r2.z; c2.w += r2.w;
            c3.x += r3.x; c3.y += r3.y; c3.z += r3.z; c3.w += r3.w;
            recE[e] = pack_rec(src, a0, a1, a2);
        }
    }

    // ---- column-sum reduce: regs -> LDS [256][17] -> 64 threads -> 16 ----
    float* cs = lds;                 // 256*17
    float* cw = lds + 256 * 17;      // 64
    cs[t * 17 + 0] = c0.x; cs[t * 17 + 1] = c0.y; cs[t * 17 + 2] = c0.z; cs[t * 17 + 3] = c0.w;
    cs[t * 17 + 4] = c1.x; cs[t * 17 + 5] = c1.y; cs[t * 17 + 6] = c1.z; cs[t * 17 + 7] = c1.w;
    cs[t * 17 + 8] = c2.x; cs[t * 17 + 9] = c2.y; cs[t * 17 + 10] = c2.z; cs[t * 17 + 11] = c2.w;
    cs[t * 17 + 12] = c3.x; cs[t * 17 + 13] = c3.y; cs[t * 17 + 14] = c3.z; cs[t * 17 + 15] = c3.w;
    __syncthreads();
    if (t < 64) {
        int f = t & 15, g = t >> 4;
        float s = 0.f;
        for (int r = 0; r < 64; ++r) s += cs[(g * 64 + r) * 17 + f];
        cw[t] = s;
    }
    __syncthreads();
    if (t < 16)
        partials[blockIdx.x * 16 + t] = cw[t] + cw[16 + t] + cw[32 + t] + cw[48 + t];
}

// ---------------- partials -> sE ; bucket bases from bcnt scan (2 bins/thread) ----------------
__global__ void k_u2(const float* __restrict__ partials, int NB,
                     const float* __restrict__ suG,
                     float* sE, int FE, float invE,
                     const int* __restrict__ bcnt,
                     int* bfill /* padded */, int* bbase, int NBK, int E) {
    __shared__ float red[256 * 4];
    __shared__ float mea[16];
    __shared__ int ib[256];
    int t = threadIdx.x;
    const float4* p4 = (const float4*)partials;
    int tot4 = NB * 4;
    float4 acc = make_float4(0.f, 0.f, 0.f, 0.f);
    for (int i = t; i < tot4; i += 256) {
        float4 v = p4[i];
        acc.x += v.x; acc.y += v.y; acc.z += v.z; acc.w += v.w;
    }
    red[t * 4 + 0] = acc.x; red[t * 4 + 1] = acc.y;
    red[t * 4 + 2] = acc.z; red[t * 4 + 3] = acc.w;
    // exclusive scan of bucket counts (2 bins per thread) -> edge base per bucket
    int i0 = 2 * t, i1 = 2 * t + 1;
    int c0 = (i0 < NBK) ? bcnt[i0] : 0;
    int c1 = (i1 < NBK) ? bcnt[i1] : 0;
    ib[t] = c0 + c1;
    __syncthreads();
    for (int d = 1; d < 256; d <<= 1) {
        int x = (t >= d) ? ib[t - d] : 0;
        __syncthreads();
        ib[t] += x;
        __syncthreads();
    }
    int excl = ib[t] - (c0 + c1);
    if (i0 < NBK) { bbase[i0] = excl;      bfill[i0 * 16] = excl; }
    if (i1 < NBK) { bbase[i1] = excl + c0; bfill[i1 * 16] = excl + c0; }
    if (t == 0) bbase[NBK] = E;
    if (t < 16) {
        int q = t >> 2, j = t & 3;
        float s = 0.f;
        for (int k = 0; k < 64; ++k) s += red[(q + k * 4) * 4 + j];
        mea[q * 4 + j] = s * invE;  // mean_ea
    }
    __syncthreads();
    if (t < 3) {
        float a = 0.f;
        for (int f = 0; f < FE; ++f) a += mea[f] * suG[t * FE + f];
        sE[t] = a;
    }
}

// ---------------- pass 2: bin records by dst bucket (counts from bhist, no first pass) --------
__global__ void k_bucket(const int* __restrict__ ei, const u64* __restrict__ recE,
                         int E, int chunk, int* bfill /* padded */,
                         u64* __restrict__ binned, unsigned char* __restrict__ bdstl,
                         int NBK, const int* __restrict__ bhist) {
    __shared__ int gb[MAXNBK], lrank[MAXNBK];
    int t = threadIdx.x;
    int cb = blockIdx.x;
    for (int i = t; i < NBK; i += 256) {
        int c = bhist[(size_t)i * NPREB + cb];
        lrank[i] = 0;
        gb[i] = c ? atomicAdd(&bfill[i * 16], c) : 0;
    }
    __syncthreads();
    int lo = cb * chunk, hi = min(E, lo + chunk);
    for (int e = lo + t; e < hi; e += 256) {
        u64 r = recE[e];
        int dst = ei[E + e];
        int b = dst >> 7;
        int rank = atomicAdd(&lrank[b], 1);
        int pos = gb[b] + rank;
        binned[pos] = r;
        bdstl[pos] = (unsigned char)(dst & 127);
    }
}

// ---------------- pass 3: per-128-node-bucket hist+scan -> row_ptr, self-loop, distribute ----------------
__global__ void k_sort(const int* __restrict__ bbase, const u64* __restrict__ binned,
                       const unsigned char* __restrict__ bdstl,
                       const float* __restrict__ sE,
                       int* __restrict__ row_ptr,
                       u64* __restrict__ rec, int N, int E) {
    __shared__ int lcnt[128], lfill[128];
    int b = blockIdx.x, t = threadIdx.x;
    int base = bbase[b], nrec = bbase[b + 1] - base;
    if (t < 128) lcnt[t] = 0;
    __syncthreads();
    for (int i = t; i < nrec; i += 256)
        atomicAdd(&lcnt[bdstl[base + i]], 1);
    __syncthreads();
    int v = (t < 128) ? lcnt[t] : 0;
    for (int d = 1; d < 128; d <<= 1) {
        int x = (t >= d && t < 128) ? lcnt[t - d] : 0;
        __syncthreads();
        if (t < 128) lcnt[t] += x;
        __syncthreads();
    }
    int gnode = (b << 7) + t;
    if (t < 128) {
        int rp = base + gnode + (lcnt[t] - v);
        if (gnode < N) {
            row_ptr[gnode] = rp;
            rec[rp] = pack_rec(gnode, sE[0], sE[1], sE[2]);  // self-loop at slot 0
        }
        lfill[t] = rp + 1;
    }
    if (b == 0 && t == 0) row_ptr[N] = E + N;
    __syncthreads();
    for (int i = t; i < nrec; i += 256) {
        u64 r = binned[base + i];
        int dl = bdstl[base + i];
        int p = atomicAdd(&lfill[dl], 1);
        rec[p] = r;
    }
}

// ---------------- MFMA GEMM: h(f16) = x @ W ; wt staged from pre-transposed f16 WT ----------
__global__ void k_gemm(const void* __restrict__ xin, int in_f16,
                       const f16* __restrict__ WT,
                       const float* __restrict__ a_s, const float* __restrict__ a_d,
                       __half* __restrict__ h, float* __restrict__ as_n,
                       float* __restrict__ ad_n, int N, int K) {
    extern __shared__ char smem[];
    const int SK = K + 8;
    f16* xs = (f16*)smem;          // 64*SK
    f16* wt = xs + 64 * SK;        // 64*SK
    int t = threadIdx.x;
    int nb = blockIdx.x * 64;

    int nK4 = K >> 2;
    if (in_f16) {
        const __half* xh = (const __half*)xin;
        for (int i = t; i < 64 * nK4; i += 256) {
            int row = i / nK4, c4 = i % nK4;
            int gr = nb + row; if (gr >= N) gr = N - 1;
            u64 v = ((const u64*)(xh + (size_t)gr * K))[c4];
            *(u64*)&xs[row * SK + c4 * 4] = v;
        }
    } else {
        const float* xf = (const float*)xin;
        for (int i = t; i < 64 * nK4; i += 256) {
            int row = i / nK4, c4 = i % nK4;
            int gr = nb + row; if (gr >= N) gr = N - 1;
            float4 v = ((const float4*)(xf + (size_t)gr * K))[c4];
            f16* p = &xs[row * SK + c4 * 4];
            p[0] = (f16)v.x; p[1] = (f16)v.y; p[2] = (f16)v.z; p[3] = (f16)v.w;
        }
    }
    // wt copy from pre-transposed f16 WT (coalesced u64, no cvt)
    for (int i = t; i < 64 * nK4; i += 256) {
        int c = i / nK4, c4 = i % nK4;
        u64 v = ((const u64*)(WT + (size_t)c * K))[c4];
        *(u64*)&wt[c * SK + c4 * 4] = v;
    }
    __syncthreads();

    int wv = t >> 6, lane = t & 63;
    int m = lane & 15, quad = lane >> 4;
    int rowA = wv * 16 + m;

    f32x4 acc[4];
#pragma unroll
    for (int ct = 0; ct < 4; ++ct) acc[ct] = (f32x4){0.f, 0.f, 0.f, 0.f};

    for (int ks = 0; ks < (K >> 5); ++ks) {
        f16x8 a = *(const f16x8*)&xs[rowA * SK + ks * 32 + quad * 8];
#pragma unroll
        for (int ct = 0; ct < 4; ++ct) {
            f16x8 bf = *(const f16x8*)&wt[(ct * 16 + m) * SK + ks * 32 + quad * 8];
            acc[ct] = __builtin_amdgcn_mfma_f32_16x16x32_f16(a, bf, acc[ct], 0, 0, 0);
        }
    }

    // as_n/ad_n directly from f32 accumulators: lane holds cols {m,16+m,32+m,48+m}
    {
        float as_c[4], ad_c[4];
#pragma unroll
        for (int ct = 0; ct < 4; ++ct) {
            as_c[ct] = a_s[ct * 16 + m];
            ad_c[ct] = a_d[ct * 16 + m];
        }
#pragma unroll
        for (int r = 0; r < 4; ++r) {
            float ps = acc[0][r] * as_c[0] + acc[1][r] * as_c[1]
                     + acc[2][r] * as_c[2] + acc[3][r] * as_c[3];
            float pd = acc[0][r] * ad_c[0] + acc[1][r] * ad_c[1]
                     + acc[2][r] * ad_c[2] + acc[3][r] * ad_c[3];
#pragma unroll
            for (int dd = 8; dd; dd >>= 1) {
                ps += __shfl_xor(ps, dd, 64);
                pd += __shfl_xor(pd, dd, 64);
            }
            if (m == 0) {
                int gr = nb + wv * 16 + quad * 4 + r;
                if (gr < N) { as_n[gr] = ps; ad_n[gr] = pd; }
            }
        }
    }

    __syncthreads();
    f16* ht = xs;
    const int HS = 72;
#pragma unroll
    for (int ct = 0; ct < 4; ++ct)
#pragma unroll
        for (int r = 0; r < 4; ++r) {
            int rl = wv * 16 + quad * 4 + r;
            ht[rl * HS + ct * 16 + m] = (f16)acc[ct][r];
        }
    __syncthreads();

    {
        int row = t >> 2, cb = (t & 3) * 16;
        int gr = nb + row;
        if (gr < N) {
            ulonglong2 v0 = *(const ulonglong2*)&ht[row * HS + cb];
            ulonglong2 v1 = *(const ulonglong2*)&ht[row * HS + cb + 8];
            *(ulonglong2*)(h + (size_t)gr * HD + cb) = v0;
            *(ulonglong2*)(h + (size_t)gr * HD + cb + 8) = v1;
        }
    }
}

// ---------------- per-node aggregation: 2 nodes/wave (32-lane sub-waves), 4 edges/iter/node ----
__global__ void k_aggr(const __half* __restrict__ h, const float* __restrict__ as_n,
                       const float* __restrict__ ad_n, const int* __restrict__ row_ptr,
                       const u64* __restrict__ rec, int l,
                       const float* __restrict__ b, __half* __restrict__ x_out,
                       float* __restrict__ emb, int N, int first) {
    int wave = threadIdx.x >> 6, lane = threadIdx.x & 63;
    int hl = lane & 31;                     // lane within half-wave
    int n = blockIdx.x * 8 + wave * 2 + (lane >> 5);
    int nc = min(n, N - 1);
    int base = row_ptr[nc], end = row_ptr[nc + 1];
    float adv = ad_n[nc];
    const int shift = 16 * (l + 1);
    int qq = (lane >> 3) & 3, fo = lane & 7;  // edge subgroup (4/half) / feature octet
    // unified chunk count across the two halves
    int nch = (end - base + 31) >> 5;
    int nchmax = max(nch, __shfl_xor(nch, 32, 64));
    float m = -INFINITY, d = 0.f;
    float acc[8];
#pragma unroll
    for (int k = 0; k < 8; ++k) acc[k] = 0.f;

    for (int ch = 0; ch < nchmax; ++ch) {
        int c = base + (ch << 5);
        int cnt = min(32, end - c);          // <=0 when own half is done
        float a = -INFINITY;
        int s = 0;
        if (hl < cnt) {
            u64 r = rec[c + hl];
            s = (int)(r & 0xFFFFull);
            float aE = __half2float(__ushort_as_half((unsigned short)(r >> shift)));
            a = as_n[s] + adv + aE;
            a = (a > 0.f) ? a : 0.2f * a;
        }
        float mc = a;
#pragma unroll
        for (int dd = 16; dd; dd >>= 1) mc = fmaxf(mc, __shfl_xor(mc, dd, 64));
        float mn = fmaxf(m, mc);
        float w = (hl < cnt) ? __expf(a - mn) : 0.f;
        float dc = w;
#pragma unroll
        for (int dd = 16; dd; dd >>= 1) dc += __shfl_xor(dc, dd, 64);
        float sc = __expf(m - mn);
        d = d * sc + dc;
#pragma unroll
        for (int k = 0; k < 8; ++k) acc[k] *= sc;
        m = mn;
        int iters = (max(cnt, 0) + 3) >> 2;
        for (int j4 = 0; j4 < iters; ++j4) {
            int j = (j4 << 2) + qq;          // j <= 31; lanes j>=cnt carry w=0,s=0
            int sl = (lane & 32) + j;        // source lane in own half
            int sj = __shfl(s, sl, 64);
            float wj = __shfl(w, sl, 64);
            uint4 hv = *(const uint4*)(h + (size_t)sj * HD + (fo << 3));
            asm("v_fma_mix_f32 %0, %1, %2, %0 op_sel:[0,0,0] op_sel_hi:[0,1,0]"
                : "+v"(acc[0]) : "v"(wj), "v"(hv.x));
            asm("v_fma_mix_f32 %0, %1, %2, %0 op_sel:[0,1,0] op_sel_hi:[0,1,0]"
                : "+v"(acc[1]) : "v"(wj), "v"(hv.x));
            asm("v_fma_mix_f32 %0, %1, %2, %0 op_sel:[0,0,0] op_sel_hi:[0,1,0]"
                : "+v"(acc[2]) : "v"(wj), "v"(hv.y));
            asm("v_fma_mix_f32 %0, %1, %2, %0 op_sel:[0,1,0] op_sel_hi:[0,1,0]"
                : "+v"(acc[3]) : "v"(wj), "v"(hv.y));
            asm("v_fma_mix_f32 %0, %1, %2, %0 op_sel:[0,0,0] op_sel_hi:[0,1,0]"
                : "+v"(acc[4]) : "v"(wj), "v"(hv.z));
            asm("v_fma_mix_f32 %0, %1, %2, %0 op_sel:[0,1,0] op_sel_hi:[0,1,0]"
                : "+v"(acc[5]) : "v"(wj), "v"(hv.z));
            asm("v_fma_mix_f32 %0, %1, %2, %0 op_sel:[0,0,0] op_sel_hi:[0,1,0]"
                : "+v"(acc[6]) : "v"(wj), "v"(hv.w));
            asm("v_fma_mix_f32 %0, %1, %2, %0 op_sel:[0,1,0] op_sel_hi:[0,1,0]"
                : "+v"(acc[7]) : "v"(wj), "v"(hv.w));
        }
    }

    // combine the 4 edge subgroups of each half (qq = lane bits 3..4)
#pragma unroll
    for (int k = 0; k < 8; ++k) {
        acc[k] += __shfl_xor(acc[k], 8, 64);
        acc[k] += __shfl_xor(acc[k], 16, 64);
    }
    if (hl < 8 && n < N) {
        float inv = 1.f / (d + 1e-16f);
        const float4* b4p = (const float4*)(b + (fo << 3));
        float4 b0 = b4p[0], b1 = b4p[1];
        float bb[8] = {b0.x, b0.y, b0.z, b0.w, b1.x, b1.y, b1.z, b1.w};
        float vv[8];
#pragma unroll
        for (int k = 0; k < 8; ++k) {
            float v = acc[k] * inv + bb[k];
            vv[k] = (v > 0.f) ? v : expm1f(v);
        }
        union { unsigned short us[8]; ulonglong2 u2; } ou;
#pragma unroll
        for (int k = 0; k < 8; ++k) ou.us[k] = __half_as_ushort(__float2half(vv[k]));
        *(ulonglong2*)(x_out + (size_t)n * HD + (fo << 3)) = ou.u2;
        float4* ep = (float4*)(emb + (size_t)n * HD + (fo << 3));
        if (first) {
            ep[0] = make_float4(vv[0], vv[1], vv[2], vv[3]);
            ep[1] = make_float4(vv[4], vv[5], vv[6], vv[7]);
        } else {
            float4 e0 = ep[0], e1 = ep[1];
            e0.x += vv[0]; e0.y += vv[1]; e0.z += vv[2]; e0.w += vv[3];
            e1.x += vv[4]; e1.y += vv[5]; e1.z += vv[6]; e1.w += vv[7];
            ep[0] = e0; ep[1] = e1;
        }
    }
}

// ---------------- column sums of emb -> gacc ; last block writes graph embedding ----------------
__global__ void k_red(float* __restrict__ emb, float* __restrict__ gacc,
                      int* __restrict__ tick, int N) {
    __shared__ float lds[256];
    __shared__ int lastf;
    int f = threadIdx.x & 63, w = threadIdx.x >> 6;
    float s = 0.f;
    for (int n = blockIdx.x * 4 + w; n < N; n += gridDim.x * 4)
        s += emb[(size_t)n * HD + f];
    lds[threadIdx.x] = s;
    __syncthreads();
    if (w == 0) {
        float v = lds[f] + lds[64 + f] + lds[128 + f] + lds[192 + f];
        atomicAdd(&gacc[f], v);
    }
    __syncthreads();
    __threadfence();
    if (threadIdx.x == 0)
        lastf = (atomicAdd(tick, 1) == (int)gridDim.x - 1);
    __syncthreads();
    if (lastf && threadIdx.x < HD) {
        float g = __hip_atomic_load(&gacc[threadIdx.x], __ATOMIC_RELAXED,
                                    __HIP_MEMORY_SCOPE_AGENT);
        emb[(size_t)N * HD + threadIdx.x] = g / (float)N;
    }
}

extern "C" void kernel_launch(void* const* d_in, const int* in_sizes, int n_in,
                              void* d_out, int out_size, void* d_ws, size_t ws_size,
                              hipStream_t stream) {
    const float* x = (const float*)d_in[0];
    const int* ei = (const int*)d_in[1];
    const float* ea = (const float*)d_in[2];

    const int FIN = in_sizes[3] / HD;       // W1 is [F_IN, 64]
    const int N = in_sizes[0] / FIN;
    const int E = in_sizes[1] / 2;
    const int FE = in_sizes[2] / E;
    const int NBK = (N + 127) >> 7;         // dst buckets of 128 nodes

    const float* W[3];  const float* as_[3]; const float* ad_[3];
    const float* We[3]; const float* ae_[3]; const float* bb[3];
    for (int l = 0; l < 3; ++l) {
        W[l]  = (const float*)d_in[3 + 6 * l + 0];
        as_[l] = (const float*)d_in[3 + 6 * l + 1];
        ad_[l] = (const float*)d_in[3 + 6 * l + 2];
        We[l] = (const float*)d_in[3 + 6 * l + 3];
        ae_[l] = (const float*)d_in[3 + 6 * l + 4];
        bb[l] = (const float*)d_in[3 + 6 * l + 5];
    }

    int ntiles = (E + 1023) / 1024;         // 1024-edge alpha tiles
    int chunk = (E + NPREB - 1) / NPREB;

    // ---- workspace layout (bytes, 256-aligned) ----
    char* ws = (char*)d_ws;
    size_t off = 0;
    auto alloc = [&](size_t bytes) {
        void* p = ws + off;
        off += (bytes + 255) & ~(size_t)255;
        return p;
    };
    __half* h      = (__half*)alloc((size_t)N * HD * 2);
    __half* x_cur  = (__half*)alloc((size_t)N * HD * 2);
    float*  as_n   = (float*)alloc((size_t)N * 4);
    float*  ad_n   = (float*)alloc((size_t)N * 4);
    int*    rowp   = (int*)alloc((size_t)(N + 1) * 4);
    int*    bcnt   = (int*)alloc((size_t)MAXNBK * 4);
    int*    bfill  = (int*)alloc((size_t)MAXNBK * 16 * 4);  // padded (64B/bucket)
    int*    bbase  = (int*)alloc((size_t)(MAXNBK + 1) * 4);
    int*    bhist  = (int*)alloc((size_t)MAXNBK * NPREB * 4);  // per-chunk bin counts
    u64*    rec    = (u64*)alloc((size_t)(E + N) * 8);
    u64*    recE   = (u64*)alloc((size_t)E * 8);
    u64*    binned = (u64*)alloc((size_t)E * 8);
    unsigned char* bdstl = (unsigned char*)alloc((size_t)E);
    float*  partials = (float*)alloc((size_t)ntiles * 16 * 4);
    float*  sE     = (float*)alloc(3 * 4);
    float*  gacc   = (float*)alloc(HD * 4);
    float*  suG    = (float*)alloc(3 * 16 * 4);
    f16*    WT0    = (f16*)alloc((size_t)HD * FIN * 2);
    f16*    WT1    = (f16*)alloc((size_t)HD * HD * 2);
    f16*    WT2    = (f16*)alloc((size_t)HD * HD * 2);
    int*    tick   = (int*)alloc(4);
    (void)ws_size; (void)n_in; (void)out_size;

    float* emb = (float*)d_out;

    k_init<<<1, 256, 0, stream>>>(bcnt, gacc, tick, suG,
                                  We[0], ae_[0], We[1], ae_[1], We[2], ae_[2], FE,
                                  W[0], W[1], W[2], WT0, WT1, WT2, FIN);
    size_t pre_lds = (size_t)(256 * 17 + 64) * 4;  // cs + cw (alpha) / lc (hist)
    k_pre<<<ntiles + NPREB, 256, pre_lds, stream>>>(ei, ea, suG, E, FE, recE, partials,
                                                    ntiles, chunk, bcnt, bhist, NBK);
    k_u2<<<1, 256, 0, stream>>>(partials, ntiles, suG, sE, FE, 1.0f / (float)E,
                                bcnt, bfill, bbase, NBK, E);
    k_bucket<<<NPREB, 256, 0, stream>>>(ei, recE, E, chunk, bfill, binned, bdstl,
                                        NBK, bhist);
    k_sort<<<NBK, 256, 0, stream>>>(bbase, binned, bdstl, sE, rowp, rec, N, E);

    for (int l = 0; l < 3; ++l) {
        const void* xin = (l == 0) ? (const void*)x : (const void*)x_cur;
        int in_f16 = (l == 0) ? 0 : 1;
        int K = (l == 0) ? FIN : HD;
        const f16* WT = (l == 0) ? WT0 : (l == 1) ? WT1 : WT2;
        size_t ldsz = (size_t)(2 * 64 * (K + 8)) * 2;  // xs + wt, f16
        k_gemm<<<(N + 63) / 64, 256, ldsz, stream>>>(xin, in_f16, WT, as_[l], ad_[l],
                                                     h, as_n, ad_n, N, K);
        k_aggr<<<(N + 7) / 8, 256, 0, stream>>>(h, as_n, ad_n, rowp, rec, l,
                                                bb[l], x_cur, emb, N, (l == 0) ? 1 : 0);
    }

    k_red<<<256, 256, 0, stream>>>(emb, gacc, tick, N);
}

// Round 11
// 344.211 us; speedup vs baseline: 5.3219x; 1.0514x over previous
//
#include <hip/hip_runtime.h>
#include <hip/hip_fp16.h>
#include <math.h>

#define HD 64       // hidden dim H
#define MAXNBK 512  // max dst-range buckets (128 nodes per bucket)
#define NPREB 512   // hist/bucket chunk blocks

typedef unsigned long long u64;
typedef _Float16 f16;
typedef _Float16 f16x8 __attribute__((ext_vector_type(8)));
typedef float f32x4 __attribute__((ext_vector_type(4)));

__device__ __forceinline__ u64 pack_rec(int src, float a0, float a1, float a2) {
    return (u64)(src & 0xFFFF)
         | ((u64)__half_as_ushort(__float2half(a0)) << 16)
         | ((u64)__half_as_ushort(__float2half(a1)) << 32)
         | ((u64)__half_as_ushort(__float2half(a2)) << 48);
}

// ---------------- init: zero bcnt/gacc/tick ; precompute su = We@ae (3 layers) ----------------
__global__ void k_init(int* bcnt, float* gacc, int* tick, float* suG,
                       const float* We1, const float* ae1,
                       const float* We2, const float* ae2,
                       const float* We3, const float* ae3, int FE) {
    int t = threadIdx.x;
    for (int i = t; i < MAXNBK; i += 256) bcnt[i] = 0;
    if (t < HD) gacc[t] = 0.f;
    if (t == 0) *tick = 0;
    if (t < 3 * FE) {
        int l = t / FE, f = t % FE;
        const float* We = (l == 0) ? We1 : (l == 1) ? We2 : We3;
        const float* ae = (l == 0) ? ae1 : (l == 1) ? ae2 : ae3;
        float s = 0.f;
        for (int hh = 0; hh < HD; ++hh) s += We[f * HD + hh] * ae[hh];
        suG[t] = s;
    }
}

// ---------------- fused: [0,nt) alpha tiles (1024 edges, LDS-free stream) ;
//                  [nt,+NPREB) dst-bucket histogram (writes bhist slice + bcnt) --------------
__global__ void k_pre(const int* __restrict__ ei, const float* __restrict__ ea,
                      const float* __restrict__ suG,
                      int E, int FE, u64* __restrict__ recE,
                      float* __restrict__ partials,
                      int nt, int chunk, int* bcnt, int* __restrict__ bhist, int NBK) {
    extern __shared__ float lds[];
    int t = threadIdx.x;

    if (blockIdx.x >= nt) {
        // ---- dst-bucket histogram chunk ----
        int* lc = (int*)lds;
        for (int i = t; i < NBK; i += 256) lc[i] = 0;
        __syncthreads();
        int cb = blockIdx.x - nt;
        int lo = cb * chunk, hi = min(E, lo + chunk);
        for (int e = lo + t; e < hi; e += 256)
            atomicAdd(&lc[ei[E + e] >> 7], 1);
        __syncthreads();
        for (int i = t; i < NBK; i += 256) {
            int c = lc[i];
            bhist[(size_t)i * NPREB + cb] = c;   // bin-major slice for k_bucket
            if (c) atomicAdd(&bcnt[i], c);       // totals for k_u2
        }
        return;
    }

    // ---- alpha tile: 1024 edges, 4 per thread, registers only ----
    size_t ebase = (size_t)blockIdx.x * 1024;
    float4 c0 = make_float4(0.f, 0.f, 0.f, 0.f), c1 = c0, c2 = c0, c3 = c0;

#pragma unroll
    for (int k = 0; k < 4; ++k) {
        size_t e = ebase + (size_t)k * 256 + t;
        bool ok = e < (size_t)E;
        size_t ec = ok ? e : (size_t)(E - 1);
        const float4* row = (const float4*)(ea + ec * FE);
        float4 r0 = row[0], r1 = row[1], r2 = row[2], r3 = row[3];
        int src = ei[ec];
        float rr[16];
        *(float4*)&rr[0] = r0; *(float4*)&rr[4] = r1;
        *(float4*)&rr[8] = r2; *(float4*)&rr[12] = r3;
        float a0 = 0.f, a1 = 0.f, a2 = 0.f;
#pragma unroll
        for (int f = 0; f < 16; ++f) {
            float v = rr[f];
            a0 += v * suG[f];
            a1 += v * suG[16 + f];
            a2 += v * suG[32 + f];
        }
        if (ok) {
            c0.x += r0.x; c0.y += r0.y; c0.z += r0.z; c0.w += r0.w;
            c1.x += r1.x; c1.y += r1.y; c1.z += r1.z; c1.w += r1.w;
            c2.x += r2.x; c2.y += r2.y; c2.z += r2.z; c2.w += r2.w;
            c3.x += r3.x; c3.y += r3.y; c3.z += r3.z; c3.w += r3.w;
            recE[e] = pack_rec(src, a0, a1, a2);
        }
    }

    // ---- column-sum reduce: regs -> LDS [256][17] -> 64 threads -> 16 ----
    float* cs = lds;                 // 256*17
    float* cw = lds + 256 * 17;      // 64
    cs[t * 17 + 0] = c0.x; cs[t * 17 + 1] = c0.y; cs[t * 17 + 2] = c0.z; cs[t * 17 + 3] = c0.w;
    cs[t * 17 + 4] = c1.x; cs[t * 17 + 5] = c1.y; cs[t * 17 + 6] = c1.z; cs[t * 17 + 7] = c1.w;
    cs[t * 17 + 8] = c2.x; cs[t * 17 + 9] = c2.y; cs[t * 17 + 10] = c2.z; cs[t * 17 + 11] = c2.w;
    cs[t * 17 + 12] = c3.x; cs[t * 17 + 13] = c3.y; cs[t * 17 + 14] = c3.z; cs[t * 17 + 15] = c3.w;
    __syncthreads();
    if (t < 64) {
        int f = t & 15, g = t >> 4;
        float s = 0.f;
        for (int r = 0; r < 64; ++r) s += cs[(g * 64 + r) * 17 + f];
        cw[t] = s;
    }
    __syncthreads();
    if (t < 16)
        partials[blockIdx.x * 16 + t] = cw[t] + cw[16 + t] + cw[32 + t] + cw[48 + t];
}

// ---------------- partials -> sE ; bucket bases from bcnt scan (2 bins/thread) ----------------
__global__ void k_u2(const float* __restrict__ partials, int NB,
                     const float* __restrict__ suG,
                     float* sE, int FE, float invE,
                     const int* __restrict__ bcnt,
                     int* bfill /* padded */, int* bbase, int NBK, int E) {
    __shared__ float red[256 * 4];
    __shared__ float mea[16];
    __shared__ int ib[256];
    int t = threadIdx.x;
    const float4* p4 = (const float4*)partials;
    int tot4 = NB * 4;
    float4 acc = make_float4(0.f, 0.f, 0.f, 0.f);
    for (int i = t; i < tot4; i += 256) {
        float4 v = p4[i];
        acc.x += v.x; acc.y += v.y; acc.z += v.z; acc.w += v.w;
    }
    red[t * 4 + 0] = acc.x; red[t * 4 + 1] = acc.y;
    red[t * 4 + 2] = acc.z; red[t * 4 + 3] = acc.w;
    // exclusive scan of bucket counts (2 bins per thread) -> edge base per bucket
    int i0 = 2 * t, i1 = 2 * t + 1;
    int c0 = (i0 < NBK) ? bcnt[i0] : 0;
    int c1 = (i1 < NBK) ? bcnt[i1] : 0;
    ib[t] = c0 + c1;
    __syncthreads();
    for (int d = 1; d < 256; d <<= 1) {
        int x = (t >= d) ? ib[t - d] : 0;
        __syncthreads();
        ib[t] += x;
        __syncthreads();
    }
    int excl = ib[t] - (c0 + c1);
    if (i0 < NBK) { bbase[i0] = excl;      bfill[i0 * 16] = excl; }
    if (i1 < NBK) { bbase[i1] = excl + c0; bfill[i1 * 16] = excl + c0; }
    if (t == 0) bbase[NBK] = E;
    if (t < 16) {
        int q = t >> 2, j = t & 3;
        float s = 0.f;
        for (int k = 0; k < 64; ++k) s += red[(q + k * 4) * 4 + j];
        mea[q * 4 + j] = s * invE;  // mean_ea
    }
    __syncthreads();
    if (t < 3) {
        float a = 0.f;
        for (int f = 0; f < FE; ++f) a += mea[f] * suG[t * FE + f];
        sE[t] = a;
    }
}

// ---------------- pass 2: bin records by dst bucket (counts from bhist, no first pass) --------
__global__ void k_bucket(const int* __restrict__ ei, const u64* __restrict__ recE,
                         int E, int chunk, int* bfill /* padded */,
                         u64* __restrict__ binned, unsigned char* __restrict__ bdstl,
                         int NBK, const int* __restrict__ bhist) {
    __shared__ int gb[MAXNBK], lrank[MAXNBK];
    int t = threadIdx.x;
    int cb = blockIdx.x;
    for (int i = t; i < NBK; i += 256) {
        int c = bhist[(size_t)i * NPREB + cb];
        lrank[i] = 0;
        gb[i] = c ? atomicAdd(&bfill[i * 16], c) : 0;
    }
    __syncthreads();
    int lo = cb * chunk, hi = min(E, lo + chunk);
    for (int e = lo + t; e < hi; e += 256) {
        u64 r = recE[e];
        int dst = ei[E + e];
        int b = dst >> 7;
        int rank = atomicAdd(&lrank[b], 1);
        int pos = gb[b] + rank;
        binned[pos] = r;
        bdstl[pos] = (unsigned char)(dst & 127);
    }
}

// ---------------- pass 3: per-128-node-bucket hist+scan -> row_ptr, self-loop, distribute ----------------
__global__ void k_sort(const int* __restrict__ bbase, const u64* __restrict__ binned,
                       const unsigned char* __restrict__ bdstl,
                       const float* __restrict__ sE,
                       int* __restrict__ row_ptr,
                       u64* __restrict__ rec, int N, int E) {
    __shared__ int lcnt[128], lfill[128];
    int b = blockIdx.x, t = threadIdx.x;
    int base = bbase[b], nrec = bbase[b + 1] - base;
    if (t < 128) lcnt[t] = 0;
    __syncthreads();
    for (int i = t; i < nrec; i += 256)
        atomicAdd(&lcnt[bdstl[base + i]], 1);
    __syncthreads();
    int v = (t < 128) ? lcnt[t] : 0;
    for (int d = 1; d < 128; d <<= 1) {
        int x = (t >= d && t < 128) ? lcnt[t - d] : 0;
        __syncthreads();
        if (t < 128) lcnt[t] += x;
        __syncthreads();
    }
    int gnode = (b << 7) + t;
    if (t < 128) {
        int rp = base + gnode + (lcnt[t] - v);
        if (gnode < N) {
            row_ptr[gnode] = rp;
            rec[rp] = pack_rec(gnode, sE[0], sE[1], sE[2]);  // self-loop at slot 0
        }
        lfill[t] = rp + 1;
    }
    if (b == 0 && t == 0) row_ptr[N] = E + N;
    __syncthreads();
    for (int i = t; i < nrec; i += 256) {
        u64 r = binned[base + i];
        int dl = bdstl[base + i];
        int p = atomicAdd(&lfill[dl], 1);
        rec[p] = r;
    }
}

// ---------------- MFMA GEMM: h(f16) = x @ W ; as_n/ad_n from f32 accumulators ----------------
__global__ void k_gemm(const void* __restrict__ xin, int in_f16,
                       const float* __restrict__ W,
                       const float* __restrict__ a_s, const float* __restrict__ a_d,
                       __half* __restrict__ h, float* __restrict__ as_n,
                       float* __restrict__ ad_n, int N, int K) {
    extern __shared__ char smem[];
    const int SK = K + 8;
    f16* xs = (f16*)smem;          // 64*SK
    f16* wt = xs + 64 * SK;        // 64*SK
    int t = threadIdx.x;
    int nb = blockIdx.x * 64;

    int nK4 = K >> 2;
    if (in_f16) {
        const __half* xh = (const __half*)xin;
        for (int i = t; i < 64 * nK4; i += 256) {
            int row = i / nK4, c4 = i % nK4;
            int gr = nb + row; if (gr >= N) gr = N - 1;
            u64 v = ((const u64*)(xh + (size_t)gr * K))[c4];
            *(u64*)&xs[row * SK + c4 * 4] = v;
        }
    } else {
        const float* xf = (const float*)xin;
        for (int i = t; i < 64 * nK4; i += 256) {
            int row = i / nK4, c4 = i % nK4;
            int gr = nb + row; if (gr >= N) gr = N - 1;
            float4 v = ((const float4*)(xf + (size_t)gr * K))[c4];
            f16* p = &xs[row * SK + c4 * 4];
            p[0] = (f16)v.x; p[1] = (f16)v.y; p[2] = (f16)v.z; p[3] = (f16)v.w;
        }
    }
    for (int i = t; i < K * 64; i += 256) {
        int k = i >> 6, c = i & 63;
        wt[c * SK + k] = (f16)W[i];
    }
    __syncthreads();

    int wv = t >> 6, lane = t & 63;
    int m = lane & 15, quad = lane >> 4;
    int rowA = wv * 16 + m;

    f32x4 acc[4];
#pragma unroll
    for (int ct = 0; ct < 4; ++ct) acc[ct] = (f32x4){0.f, 0.f, 0.f, 0.f};

    for (int ks = 0; ks < (K >> 5); ++ks) {
        f16x8 a = *(const f16x8*)&xs[rowA * SK + ks * 32 + quad * 8];
#pragma unroll
        for (int ct = 0; ct < 4; ++ct) {
            f16x8 bf = *(const f16x8*)&wt[(ct * 16 + m) * SK + ks * 32 + quad * 8];
            acc[ct] = __builtin_amdgcn_mfma_f32_16x16x32_f16(a, bf, acc[ct], 0, 0, 0);
        }
    }

    // as_n/ad_n directly from f32 accumulators: lane holds cols {m,16+m,32+m,48+m}
    {
        float as_c[4], ad_c[4];
#pragma unroll
        for (int ct = 0; ct < 4; ++ct) {
            as_c[ct] = a_s[ct * 16 + m];
            ad_c[ct] = a_d[ct * 16 + m];
        }
#pragma unroll
        for (int r = 0; r < 4; ++r) {
            float ps = acc[0][r] * as_c[0] + acc[1][r] * as_c[1]
                     + acc[2][r] * as_c[2] + acc[3][r] * as_c[3];
            float pd = acc[0][r] * ad_c[0] + acc[1][r] * ad_c[1]
                     + acc[2][r] * ad_c[2] + acc[3][r] * ad_c[3];
#pragma unroll
            for (int dd = 8; dd; dd >>= 1) {
                ps += __shfl_xor(ps, dd, 64);
                pd += __shfl_xor(pd, dd, 64);
            }
            if (m == 0) {
                int gr = nb + wv * 16 + quad * 4 + r;
                if (gr < N) { as_n[gr] = ps; ad_n[gr] = pd; }
            }
        }
    }

    __syncthreads();
    f16* ht = xs;
    const int HS = 72;
#pragma unroll
    for (int ct = 0; ct < 4; ++ct)
#pragma unroll
        for (int r = 0; r < 4; ++r) {
            int rl = wv * 16 + quad * 4 + r;
            ht[rl * HS + ct * 16 + m] = (f16)acc[ct][r];
        }
    __syncthreads();

    {
        int row = t >> 2, cb = (t & 3) * 16;
        int gr = nb + row;
        if (gr < N) {
            ulonglong2 v0 = *(const ulonglong2*)&ht[row * HS + cb];
            ulonglong2 v1 = *(const ulonglong2*)&ht[row * HS + cb + 8];
            *(ulonglong2*)(h + (size_t)gr * HD + cb) = v0;
            *(ulonglong2*)(h + (size_t)gr * HD + cb + 8) = v1;
        }
    }
}

// ---------------- per-node aggregation: 2 nodes/wave (32-lane sub-waves), 4 edges/iter/node ----
__global__ void k_aggr(const __half* __restrict__ h, const float* __restrict__ as_n,
                       const float* __restrict__ ad_n, const int* __restrict__ row_ptr,
                       const u64* __restrict__ rec, int l,
                       const float* __restrict__ b, __half* __restrict__ x_out,
                       float* __restrict__ emb, int N, int first) {
    int wave = threadIdx.x >> 6, lane = threadIdx.x & 63;
    int hl = lane & 31;                     // lane within half-wave
    int n = blockIdx.x * 8 + wave * 2 + (lane >> 5);
    int nc = min(n, N - 1);
    int base = row_ptr[nc], end = row_ptr[nc + 1];
    float adv = ad_n[nc];
    const int shift = 16 * (l + 1);
    int qq = (lane >> 3) & 3, fo = lane & 7;  // edge subgroup (4/half) / feature octet
    // unified chunk count across the two halves
    int nch = (end - base + 31) >> 5;
    int nchmax = max(nch, __shfl_xor(nch, 32, 64));
    float m = -INFINITY, d = 0.f;
    float acc[8];
#pragma unroll
    for (int k = 0; k < 8; ++k) acc[k] = 0.f;

    for (int ch = 0; ch < nchmax; ++ch) {
        int c = base + (ch << 5);
        int cnt = min(32, end - c);          // <=0 when own half is done
        float a = -INFINITY;
        int s = 0;
        if (hl < cnt) {
            u64 r = rec[c + hl];
            s = (int)(r & 0xFFFFull);
            float aE = __half2float(__ushort_as_half((unsigned short)(r >> shift)));
            a = as_n[s] + adv + aE;
            a = (a > 0.f) ? a : 0.2f * a;
        }
        float mc = a;
#pragma unroll
        for (int dd = 16; dd; dd >>= 1) mc = fmaxf(mc, __shfl_xor(mc, dd, 64));
        float mn = fmaxf(m, mc);
        float w = (hl < cnt) ? __expf(a - mn) : 0.f;
        float dc = w;
#pragma unroll
        for (int dd = 16; dd; dd >>= 1) dc += __shfl_xor(dc, dd, 64);
        float sc = __expf(m - mn);
        d = d * sc + dc;
#pragma unroll
        for (int k = 0; k < 8; ++k) acc[k] *= sc;
        m = mn;
        int iters = (max(cnt, 0) + 3) >> 2;
        for (int j4 = 0; j4 < iters; ++j4) {
            int j = (j4 << 2) + qq;          // j <= 31; lanes j>=cnt carry w=0,s=0
            int sl = (lane & 32) + j;        // source lane in own half
            int sj = __shfl(s, sl, 64);
            float wj = __shfl(w, sl, 64);
            uint4 hv = *(const uint4*)(h + (size_t)sj * HD + (fo << 3));
            asm("v_fma_mix_f32 %0, %1, %2, %0 op_sel:[0,0,0] op_sel_hi:[0,1,0]"
                : "+v"(acc[0]) : "v"(wj), "v"(hv.x));
            asm("v_fma_mix_f32 %0, %1, %2, %0 op_sel:[0,1,0] op_sel_hi:[0,1,0]"
                : "+v"(acc[1]) : "v"(wj), "v"(hv.x));
            asm("v_fma_mix_f32 %0, %1, %2, %0 op_sel:[0,0,0] op_sel_hi:[0,1,0]"
                : "+v"(acc[2]) : "v"(wj), "v"(hv.y));
            asm("v_fma_mix_f32 %0, %1, %2, %0 op_sel:[0,1,0] op_sel_hi:[0,1,0]"
                : "+v"(acc[3]) : "v"(wj), "v"(hv.y));
            asm("v_fma_mix_f32 %0, %1, %2, %0 op_sel:[0,0,0] op_sel_hi:[0,1,0]"
                : "+v"(acc[4]) : "v"(wj), "v"(hv.z));
            asm("v_fma_mix_f32 %0, %1, %2, %0 op_sel:[0,1,0] op_sel_hi:[0,1,0]"
                : "+v"(acc[5]) : "v"(wj), "v"(hv.z));
            asm("v_fma_mix_f32 %0, %1, %2, %0 op_sel:[0,0,0] op_sel_hi:[0,1,0]"
                : "+v"(acc[6]) : "v"(wj), "v"(hv.w));
            asm("v_fma_mix_f32 %0, %1, %2, %0 op_sel:[0,1,0] op_sel_hi:[0,1,0]"
                : "+v"(acc[7]) : "v"(wj), "v"(hv.w));
        }
    }

    // combine the 4 edge subgroups of each half (qq = lane bits 3..4)
#pragma unroll
    for (int k = 0; k < 8; ++k) {
        acc[k] += __shfl_xor(acc[k], 8, 64);
        acc[k] += __shfl_xor(acc[k], 16, 64);
    }
    if (hl < 8 && n < N) {
        float inv = 1.f / (d + 1e-16f);
        const float4* b4p = (const float4*)(b + (fo << 3));
        float4 b0 = b4p[0], b1 = b4p[1];
        float bb[8] = {b0.x, b0.y, b0.z, b0.w, b1.x, b1.y, b1.z, b1.w};
        float vv[8];
#pragma unroll
        for (int k = 0; k < 8; ++k) {
            float v = acc[k] * inv + bb[k];
            vv[k] = (v > 0.f) ? v : expm1f(v);
        }
        union { unsigned short us[8]; ulonglong2 u2; } ou;
#pragma unroll
        for (int k = 0; k < 8; ++k) ou.us[k] = __half_as_ushort(__float2half(vv[k]));
        *(ulonglong2*)(x_out + (size_t)n * HD + (fo << 3)) = ou.u2;
        float4* ep = (float4*)(emb + (size_t)n * HD + (fo << 3));
        if (first) {
            ep[0] = make_float4(vv[0], vv[1], vv[2], vv[3]);
            ep[1] = make_float4(vv[4], vv[5], vv[6], vv[7]);
        } else {
            float4 e0 = ep[0], e1 = ep[1];
            e0.x += vv[0]; e0.y += vv[1]; e0.z += vv[2]; e0.w += vv[3];
            e1.x += vv[4]; e1.y += vv[5]; e1.z += vv[6]; e1.w += vv[7];
            ep[0] = e0; ep[1] = e1;
        }
    }
}

// ---------------- column sums of emb -> gacc ; last block writes graph embedding ----------------
__global__ void k_red(float* __restrict__ emb, float* __restrict__ gacc,
                      int* __restrict__ tick, int N) {
    __shared__ float lds[256];
    __shared__ int lastf;
    int f = threadIdx.x & 63, w = threadIdx.x >> 6;
    float s = 0.f;
    for (int n = blockIdx.x * 4 + w; n < N; n += gridDim.x * 4)
        s += emb[(size_t)n * HD + f];
    lds[threadIdx.x] = s;
    __syncthreads();
    if (w == 0) {
        float v = lds[f] + lds[64 + f] + lds[128 + f] + lds[192 + f];
        atomicAdd(&gacc[f], v);
    }
    __syncthreads();
    __threadfence();
    if (threadIdx.x == 0)
        lastf = (atomicAdd(tick, 1) == (int)gridDim.x - 1);
    __syncthreads();
    if (lastf && threadIdx.x < HD) {
        float g = __hip_atomic_load(&gacc[threadIdx.x], __ATOMIC_RELAXED,
                                    __HIP_MEMORY_SCOPE_AGENT);
        emb[(size_t)N * HD + threadIdx.x] = g / (float)N;
    }
}

extern "C" void kernel_launch(void* const* d_in, const int* in_sizes, int n_in,
                              void* d_out, int out_size, void* d_ws, size_t ws_size,
                              hipStream_t stream) {
    const float* x = (const float*)d_in[0];
    const int* ei = (const int*)d_in[1];
    const float* ea = (const float*)d_in[2];

    const int FIN = in_sizes[3] / HD;       // W1 is [F_IN, 64]
    const int N = in_sizes[0] / FIN;
    const int E = in_sizes[1] / 2;
    const int FE = in_sizes[2] / E;
    const int NBK = (N + 127) >> 7;         // dst buckets of 128 nodes

    const float* W[3];  const float* as_[3]; const float* ad_[3];
    const float* We[3]; const float* ae_[3]; const float* bb[3];
    for (int l = 0; l < 3; ++l) {
        W[l]  = (const float*)d_in[3 + 6 * l + 0];
        as_[l] = (const float*)d_in[3 + 6 * l + 1];
        ad_[l] = (const float*)d_in[3 + 6 * l + 2];
        We[l] = (const float*)d_in[3 + 6 * l + 3];
        ae_[l] = (const float*)d_in[3 + 6 * l + 4];
        bb[l] = (const float*)d_in[3 + 6 * l + 5];
    }

    int ntiles = (E + 1023) / 1024;         // 1024-edge alpha tiles
    int chunk = (E + NPREB - 1) / NPREB;

    // ---- workspace layout (bytes, 256-aligned) ----
    char* ws = (char*)d_ws;
    size_t off = 0;
    auto alloc = [&](size_t bytes) {
        void* p = ws + off;
        off += (bytes + 255) & ~(size_t)255;
        return p;
    };
    __half* h      = (__half*)alloc((size_t)N * HD * 2);
    __half* x_cur  = (__half*)alloc((size_t)N * HD * 2);
    float*  as_n   = (float*)alloc((size_t)N * 4);
    float*  ad_n   = (float*)alloc((size_t)N * 4);
    int*    rowp   = (int*)alloc((size_t)(N + 1) * 4);
    int*    bcnt   = (int*)alloc((size_t)MAXNBK * 4);
    int*    bfill  = (int*)alloc((size_t)MAXNBK * 16 * 4);  // padded (64B/bucket)
    int*    bbase  = (int*)alloc((size_t)(MAXNBK + 1) * 4);
    int*    bhist  = (int*)alloc((size_t)MAXNBK * NPREB * 4);  // per-chunk bin counts
    u64*    rec    = (u64*)alloc((size_t)(E + N) * 8);
    u64*    recE   = (u64*)alloc((size_t)E * 8);
    u64*    binned = (u64*)alloc((size_t)E * 8);
    unsigned char* bdstl = (unsigned char*)alloc((size_t)E);
    float*  partials = (float*)alloc((size_t)ntiles * 16 * 4);
    float*  sE     = (float*)alloc(3 * 4);
    float*  gacc   = (float*)alloc(HD * 4);
    float*  suG    = (float*)alloc(3 * 16 * 4);
    int*    tick   = (int*)alloc(4);
    (void)ws_size; (void)n_in; (void)out_size;

    float* emb = (float*)d_out;

    k_init<<<1, 256, 0, stream>>>(bcnt, gacc, tick, suG,
                                  We[0], ae_[0], We[1], ae_[1], We[2], ae_[2], FE);
    size_t pre_lds = (size_t)(256 * 17 + 64) * 4;  // cs + cw (alpha) / lc (hist)
    k_pre<<<ntiles + NPREB, 256, pre_lds, stream>>>(ei, ea, suG, E, FE, recE, partials,
                                                    ntiles, chunk, bcnt, bhist, NBK);
    k_u2<<<1, 256, 0, stream>>>(partials, ntiles, suG, sE, FE, 1.0f / (float)E,
                                bcnt, bfill, bbase, NBK, E);
    k_bucket<<<NPREB, 256, 0, stream>>>(ei, recE, E, chunk, bfill, binned, bdstl,
                                        NBK, bhist);
    k_sort<<<NBK, 256, 0, stream>>>(bbase, binned, bdstl, sE, rowp, rec, N, E);

    for (int l = 0; l < 3; ++l) {
        const void* xin = (l == 0) ? (const void*)x : (const void*)x_cur;
        int in_f16 = (l == 0) ? 0 : 1;
        int K = (l == 0) ? FIN : HD;
        size_t ldsz = (size_t)(2 * 64 * (K + 8)) * 2;  // xs + wt, f16
        k_gemm<<<(N + 63) / 64, 256, ldsz, stream>>>(xin, in_f16, W[l], as_[l], ad_[l],
                                                     h, as_n, ad_n, N, K);
        k_aggr<<<(N + 7) / 8, 256, 0, stream>>>(h, as_n, ad_n, rowp, rec, l,
                                                bb[l], x_cur, emb, N, (l == 0) ? 1 : 0);
    }

    k_red<<<256, 256, 0, stream>>>(emb, gacc, tick, N);
}